// Round 1
// baseline (207.603 us; speedup 1.0000x reference)
//
#include <hip/hip_runtime.h>
#include <hip/hip_bf16.h>

// ---------------------------------------------------------------------------
// MMD loss:  mmd = 2*Sxx_upper/(n(n-1)) + 2*Syy_upper/(m(m-1)) - 2*Sxy/(n*m)
// k(a,b) = exp(-|a-b|^2 / 128)  (sigma^2 = D = 64), N = M = 8192, D = 64.
//
// Key algebra: store A' = A * sqrt(log2e)/8 in bf16 and s = 0.5*|a'|^2 (f32).
// Then  exp(-|a-b|^2/128) = exp2( dot(a',b') - s_a - s_b ).
// The -(s_a+s_b) term is the MFMA C-operand init, so the epilogue per element
// is just: min(acc,0) -> v_exp_f32 -> accumulate.  3 VALU-class ops/element.
//
// Mode is specialized at compile time (template<bool SYM>); mode 2 (XY) is a
// branch-free fully-unrolled body. B fragments are double-buffered in regs
// (load nt+1 before computing nt) to hide L2 latency.
// Finalize is fused: per-block double atomicAdd + arrival counter (reset by
// prep each launch); last block writes the clamped output.
// ---------------------------------------------------------------------------

using short8 = __attribute__((ext_vector_type(8))) short;  // 8 bf16 (4 VGPRs)
using f32x4  = __attribute__((ext_vector_type(4))) float;  // 4 fp32

#define NROWS 8192
#define DDIM  64
#define TOTAL_MAIN_BLOCKS (32 * 64 * 3)

// sqrt(log2(e)) / 8
#define PRESCALE 0.15014030109830622f

#if __has_builtin(__builtin_amdgcn_exp2f)
#define EXP2F(x) __builtin_amdgcn_exp2f(x)
#else
#define EXP2F(x) exp2f(x)
#endif

// ---------------------------------------------------------------------------
// Prep: normalize X, prescale, cast X/Y to bf16, compute s = 0.5*|row'|^2
// from the bf16-rounded values (consistent with the MFMA inputs).
// Also resets the fused-finalize accumulator + arrival counter.
// ---------------------------------------------------------------------------
__global__ __launch_bounds__(256) void mmd_prep(
    const float* __restrict__ z_seq, const float* __restrict__ pmean,
    const float* __restrict__ pstd, const float* __restrict__ z_prior,
    __hip_bfloat16* __restrict__ Xb, __hip_bfloat16* __restrict__ Yb,
    float* __restrict__ sxx, float* __restrict__ syy,
    double* __restrict__ acc, unsigned* __restrict__ cnt)
{
    const int tid  = threadIdx.x;
    if (blockIdx.x == 0 && tid == 0) { *acc = 0.0; *cnt = 0u; }

    const int lane = tid & 63;
    const int wid  = tid >> 6;
    const int row  = blockIdx.x * 4 + wid;   // 0..16383 (X rows then Y rows)

    float v;
    __hip_bfloat16* dst;
    float* sdst;
    int r;
    if (row < NROWS) {
        r = row;
        v = (z_seq[(size_t)r * DDIM + lane] - pmean[lane]) / pstd[lane];
        dst = Xb; sdst = sxx;
    } else {
        r = row - NROWS;
        v = z_prior[(size_t)r * DDIM + lane];
        dst = Yb; sdst = syy;
    }
    __hip_bfloat16 hb = __float2bfloat16(v * PRESCALE);
    dst[(size_t)r * DDIM + lane] = hb;

    float vb = __bfloat162float(hb);
    float sq = vb * vb;
#pragma unroll
    for (int off = 32; off; off >>= 1) sq += __shfl_xor(sq, off, 64);
    if (lane == 0) sdst[r] = 0.5f * sq;
}

// ---------------------------------------------------------------------------
// Per-thread tile compute for one 128(i) x 256(j) block; wave tile 64x128.
// SYM known at compile time; mode 2 body is branch-free straight-line code.
// ---------------------------------------------------------------------------
template<bool SYM>
__device__ __forceinline__ float mmd_block(
    const __hip_bfloat16* __restrict__ A, const __hip_bfloat16* __restrict__ Bp,
    const float* __restrict__ sa, const float* __restrict__ sb,
    int iBlock, int jBlock)
{
    const int tid  = threadIdx.x;
    const int lane = tid & 63;
    const int wid  = tid >> 6;
    const int quad = lane >> 4;
    const int l15  = lane & 15;

    const int i0 = iBlock + (wid >> 1) * 64;   // wave row origin
    const int j0 = jBlock + (wid & 1) * 128;   // wave col origin

    // Persistent A fragments + negated row norms.
    short8 af[4][2];
    f32x4  nsx[4];
#pragma unroll
    for (int mt = 0; mt < 4; ++mt) {
        const int ar = i0 + mt * 16 + l15;
#pragma unroll
        for (int ks = 0; ks < 2; ++ks)
            af[mt][ks] = *reinterpret_cast<const short8*>(
                A + (size_t)ar * DDIM + ks * 32 + quad * 8);
        f32x4 s4 = *reinterpret_cast<const f32x4*>(sa + i0 + mt * 16 + quad * 4);
        nsx[mt] = -s4;
    }

    float lsum = 0.0f;

    // B fragment double-buffer: prefetch nt, compute nt-1.
    const __hip_bfloat16* bbase = Bp + (size_t)(j0 + l15) * DDIM + quad * 8;
    const float* sbp = sb + j0 + l15;

    short8 b0 = *reinterpret_cast<const short8*>(bbase);
    short8 b1 = *reinterpret_cast<const short8*>(bbase + 32);
    float  sy = sbp[0];

#pragma unroll
    for (int nt = 0; nt < 8; ++nt) {
        const int jt = j0 + nt * 16;

        short8 nb0{}, nb1{};
        float  nsy = 0.0f;
        if (nt < 7) {
            const __hip_bfloat16* nb = bbase + (size_t)(nt + 1) * 16 * DDIM;
            nb0 = *reinterpret_cast<const short8*>(nb);
            nb1 = *reinterpret_cast<const short8*>(nb + 32);
            nsy = sbp[(nt + 1) * 16];
        }

        if (!SYM || jt >= i0) {
#pragma unroll
            for (int mt = 0; mt < 4; ++mt) {
                const int it = i0 + mt * 16;
                if (SYM && jt < it) continue;      // tile strictly below diag

                f32x4 acc;
#pragma unroll
                for (int r = 0; r < 4; ++r) acc[r] = nsx[mt][r] - sy;
                acc = __builtin_amdgcn_mfma_f32_16x16x32_bf16(af[mt][0], b0, acc, 0, 0, 0);
                acc = __builtin_amdgcn_mfma_f32_16x16x32_bf16(af[mt][1], b1, acc, 0, 0, 0);

                if (SYM && jt == it) {
                    // diagonal tile: count only j > i (trace excluded exactly)
#pragma unroll
                    for (int r = 0; r < 4; ++r) {
                        float v = EXP2F(fminf(acc[r], 0.0f));
                        lsum += (l15 > quad * 4 + r) ? v : 0.0f;
                    }
                } else {
#pragma unroll
                    for (int r = 0; r < 4; ++r)
                        lsum += EXP2F(fminf(acc[r], 0.0f));
                }
            }
        }

        if (nt < 7) { b0 = nb0; b1 = nb1; sy = nsy; }
    }
    return lsum;
}

// ---------------------------------------------------------------------------
// Main: grid (32 jblocks, 64 iblocks, 3 modes). Block tile 128(i) x 256(j),
// 4 waves in 2x2. mode 0: XX (sym), 1: YY (sym), 2: XY (full).
// Fused finalize via double atomicAdd + arrival counter.
// ---------------------------------------------------------------------------
__global__ __launch_bounds__(256) void mmd_main(
    const __hip_bfloat16* __restrict__ Xb, const __hip_bfloat16* __restrict__ Yb,
    const float* __restrict__ sxx, const float* __restrict__ syy,
    double* __restrict__ acc, unsigned* __restrict__ cnt,
    float* __restrict__ out)
{
    const int mode = blockIdx.z;
    const int bj = blockIdx.x;          // 0..31  (256-wide j blocks)
    const int bi = blockIdx.y;          // 0..63  (128-tall i blocks)
    const int iBlock = bi * 128;
    const int jBlock = bj * 256;
    const int tid = threadIdx.x;

    float lsum = 0.0f;
    const bool active = !(mode < 2 && (jBlock + 256 <= iBlock));

    if (active) {
        if (mode == 0)      lsum = mmd_block<true >(Xb, Xb, sxx, sxx, iBlock, jBlock);
        else if (mode == 1) lsum = mmd_block<true >(Yb, Yb, syy, syy, iBlock, jBlock);
        else                lsum = mmd_block<false>(Xb, Yb, sxx, syy, iBlock, jBlock);
    }

    // wave reduce
#pragma unroll
    for (int off = 32; off; off >>= 1) lsum += __shfl_xor(lsum, off, 64);

    __shared__ float ws4[4];
    const int lane = tid & 63, wid = tid >> 6;
    if (lane == 0) ws4[wid] = lsum;
    __syncthreads();
    if (tid == 0) {
        double tot = (double)ws4[0] + (double)ws4[1] + (double)ws4[2] + (double)ws4[3];
        // sym coefficient folds the x2 for sum_{i!=j} = 2 * sum_{j>i}
        const double c = (mode < 2) ? (2.0 / (8192.0 * 8191.0))
                                    : (-2.0 / (8192.0 * 8192.0));
        if (tot != 0.0) atomicAdd(acc, tot * c);
        __threadfence();
        unsigned done = atomicAdd(cnt, 1u);
        if (done == TOTAL_MAIN_BLOCKS - 1) {
            double v = atomicAdd(acc, 0.0);   // coherent read of final sum
            out[0] = (float)(v > 0.0 ? v : 0.0);
        }
    }
}

// ---------------------------------------------------------------------------
extern "C" void kernel_launch(void* const* d_in, const int* in_sizes, int n_in,
                              void* d_out, int out_size, void* d_ws, size_t ws_size,
                              hipStream_t stream) {
    const float* z_seq   = (const float*)d_in[0];   // [16,512,64]
    const float* pmean   = (const float*)d_in[1];   // [64]
    const float* pstd    = (const float*)d_in[2];   // [64]
    const float* z_prior = (const float*)d_in[3];   // [8192,64]
    float* out = (float*)d_out;

    char* ws = (char*)d_ws;
    __hip_bfloat16* Xb = (__hip_bfloat16*)(ws);                    // 1 MB
    __hip_bfloat16* Yb = (__hip_bfloat16*)(ws + (1u << 20));       // 1 MB
    float* sxx = (float*)(ws + (2u << 20));                        // 32 KB
    float* syy = (float*)(ws + (2u << 20) + 32768);                // 32 KB
    double* acc = (double*)(ws + (2u << 20) + 65536);              // 8 B
    unsigned* cnt = (unsigned*)(ws + (2u << 20) + 65536 + 64);     // 4 B

    mmd_prep<<<dim3(4096), dim3(256), 0, stream>>>(
        z_seq, pmean, pstd, z_prior, Xb, Yb, sxx, syy, acc, cnt);
    mmd_main<<<dim3(32, 64, 3), dim3(256), 0, stream>>>(
        Xb, Yb, sxx, syy, acc, cnt, out);
}